// Round 4
// baseline (85.588 us; speedup 1.0000x reference)
//
#include <hip/hip_runtime.h>
#include <hip/hip_bf16.h>

// DeformConv2d: x[4,4,256,36,36] f32, filter[1024,256,3,3] f32, offset[16,2] f32
// out[4,1024,36,36] f32.
// K-axis layout (both operands, opaque to GEMM): k' = n*256 + c  (tap-major).
// R4: sample kernel re-chunked to 32 channels/block (LDS 16.5KB -> 8 blocks/CU,
// occupancy cap 100%) + merged i-phases for load MLP. GEMM unchanged from R3.
// ws: xt [16][1296][2304] bf16 + w' [1024][2304] bf16 = 100,270,080 B.

#define HH 36
#define WW 36
#define CT 256
#define NB 16
#define KK 2304      // 9*256
#define NP 1296      // 36*36
#define OCH 1024
#define OUTG 256

typedef __attribute__((ext_vector_type(8))) short short8;
typedef __attribute__((ext_vector_type(4))) float f32x4;
typedef __attribute__((ext_vector_type(4))) unsigned short us4;

__device__ __forceinline__ unsigned short f2bf(float v) {
    unsigned u = __float_as_uint(v);
    u += 0x7fffu + ((u >> 16) & 1u);   // RNE
    return (unsigned short)(u >> 16);
}

// ---------------- kernel 1: filter fp32 [o][c*9+n] -> bf16 [o][n*256+c] ----------
__global__ __launch_bounds__(256) void cvt_filter(const float* __restrict__ f,
                                                  unsigned short* __restrict__ w) {
    const int o = blockIdx.x;
    const float* fo = f + (size_t)o * KK;
    unsigned short* wo = w + (size_t)o * KK;
    for (int k4 = threadIdx.x * 4; k4 < KK; k4 += 1024) {
        int n = k4 >> 8;          // tap
        int c = k4 & 255;         // channel (multiple of 4)
        us4 v;
#pragma unroll
        for (int cc = 0; cc < 4; ++cc) v[cc] = f2bf(fo[(c + cc) * 9 + n]);
        *reinterpret_cast<us4*>(wo + k4) = v;
    }
}

// ---------------- kernel 2: deformable bilinear sampling -> Xoff^T bf16 -----------
// grid 4608 = 16b * 8chunk * 36y (XCD-swizzled); block = 32 channels, one y.
__global__ __launch_bounds__(256) void sample_kernel(const float* __restrict__ x,
                                                     const float* __restrict__ off,
                                                     unsigned short* __restrict__ xt) {
    // bijective XCD swizzle: each XCD gets 576 consecutive wids = 2 b's
    const int wid = (blockIdx.x & 7) * 576 + (blockIdx.x >> 3);
    const int b = wid / 288;
    const int rem = wid - b * 288;
    const int chunk = rem / 36;          // 0..7
    const int y = rem - chunk * 36;
    const int c0 = chunk * 32;
    const int tid = threadIdx.x;
    const float sx = 3.0f / off[2 * b + 0];
    const float sy = 3.0f / off[2 * b + 1];

    // row (i) tables: per-thread registers (block-uniform)
    int qxl[3], qxr[3]; float gxl[3], gxr[3];
    bool lok[3], rok[3];
#pragma unroll
    for (int i = 0; i < 3; ++i) {
        float px = (float)(y + 1) + (float)(i - 1) * sx;
        float pc = fminf(fmaxf(px, 0.f), 37.f);
        float fl = floorf(px);
        float ql = fminf(fmaxf(fl, 0.f), 37.f);
        float qr = fminf(fmaxf(fl + 1.f, 0.f), 37.f);
        qxl[i] = (int)ql; qxr[i] = (int)qr;
        gxl[i] = 1.f + (ql - pc);
        gxr[i] = 1.f - (qr - pc);
        lok[i] = (qxl[i] >= 1 && qxl[i] <= 36);
        rok[i] = (qxr[i] >= 1 && qxr[i] <= 36);
    }

    // column (x,j) tables in LDS
    __shared__ int   s_qyl[HH * 3], s_qyr[HH * 3];
    __shared__ float s_gyl[HH * 3], s_gyr[HH * 3];
    if (tid < HH * 3) {
        int xx = tid / 3, j = tid % 3;
        float py = (float)(xx + 1) + (float)(j - 1) * sy;
        float pc = fminf(fmaxf(py, 0.f), 37.f);
        float fl = floorf(py);
        float ql = fminf(fmaxf(fl, 0.f), 37.f);
        float qr = fminf(fmaxf(fl + 1.f, 0.f), 37.f);
        s_qyl[tid] = (int)ql; s_qyr[tid] = (int)qr;
        s_gyl[tid] = 1.f + (ql - pc);
        s_gyr[tid] = 1.f - (qr - pc);
    }

    // row-interpolated values: xrow[c(32)][i(3)*38 + col(38)], pitch 115
    __shared__ float xrow[32 * 115];

    const float* xb = x + (size_t)(b * CT + c0) * (HH * WW);

    // phase 1: all 3 i's per element -> 6 independent loads in flight per iter
    for (int e = tid; e < 32 * 38; e += 256) {
        const int c = e / 38;
        const int col = e - c * 38;          // padded col 0..37
        const float* xc = xb + c * (HH * WW);
        const bool cok = (col >= 1 && col <= 36);
#pragma unroll
        for (int i = 0; i < 3; ++i) {
            float vl = 0.f, vr = 0.f;
            if (cok) {
                if (lok[i]) vl = xc[(qxl[i] - 1) * WW + (col - 1)];
                if (rok[i]) vr = xc[(qxr[i] - 1) * WW + (col - 1)];
            }
            xrow[c * 115 + i * 38 + col] = gxl[i] * vl + gxr[i] * vr;
        }
    }
    __syncthreads();

    // phase 2: thread (xi, cg) -> 9 taps x 4 channels, 8B stores
    for (int e = tid; e < 8 * 36; e += 256) {
        const int xi = e >> 3;
        const int cg = e & 7;
        float gl[3], gr[3]; int ql[3], qr[3];
#pragma unroll
        for (int j = 0; j < 3; ++j) {
            int t = xi * 3 + j;
            gl[j] = s_gyl[t]; gr[j] = s_gyr[t];
            ql[j] = s_qyl[t]; qr[j] = s_qyr[t];
        }
        const size_t obase = ((size_t)b * NP + y * WW + xi) * KK + c0 + cg * 4;
#pragma unroll
        for (int n = 0; n < 9; ++n) {
            const int i = n / 3, j = n % 3;
            us4 o;
#pragma unroll
            for (int cc = 0; cc < 4; ++cc) {
                const float* xr = &xrow[(cg * 4 + cc) * 115 + i * 38];
                float v = gl[j] * xr[ql[j]] + gr[j] * xr[qr[j]];
                o[cc] = f2bf(v);
            }
            *reinterpret_cast<us4*>(xt + obase + n * 256) = o;
        }
    }
}

// ---------------- kernel 3: MFMA GEMM, 128x64 tile, BK=64, dbuf, swizzled ---------
__global__ __launch_bounds__(256) void gemm_kernel(const unsigned short* __restrict__ wbf,
                                                   const unsigned short* __restrict__ xt,
                                                   float* __restrict__ out) {
    // 672 blocks = 8 XCD * 84; 84 per XCD = 2 b's worth (42 tiles per b)
    const int wid = (blockIdx.x & 7) * 84 + (blockIdx.x >> 3);
    const int b = wid / 42;
    const int rem = wid - b * 42;
    const int mt = rem / 21;
    const int nt = rem - mt * 21;
    const int m0 = mt * 128;
    const int p0 = nt * 64;
    const int g = b & 3;
    const int mimg = b >> 2;

    const unsigned short* Ab = wbf + (size_t)(g * OUTG + m0) * KK;
    const unsigned short* Bb = xt + (size_t)b * NP * KK;

    __shared__ __align__(16) unsigned short As[2][128 * 64];
    __shared__ __align__(16) unsigned short Bs[2][64 * 64];

    const int tid = threadIdx.x;
    const int wave = tid >> 6, lane = tid & 63;
    const int wr = wave >> 1, wc = wave & 1;
    const int l8 = lane >> 3;                 // staging sub-row 0..7
    const int sgrp = (lane & 7) ^ l8;         // pre-swizzled source column group

    f32x4 acc[4][2] = {};

#define STAGE(BUF, KT) do {                                                       \
    const int k0_ = (KT) * 64;                                                    \
    _Pragma("unroll")                                                             \
    for (int ii = 0; ii < 4; ++ii) {                                              \
        const int inst = wave * 4 + ii;                                           \
        const int row = inst * 8 + l8;                                            \
        const unsigned short* srcA = Ab + (size_t)row * KK + k0_ + sgrp * 8;      \
        __builtin_amdgcn_global_load_lds(                                         \
            (const __attribute__((address_space(1))) void*)srcA,                  \
            (__attribute__((address_space(3))) void*)&As[BUF][inst * 512], 16, 0, 0); \
    }                                                                             \
    _Pragma("unroll")                                                             \
    for (int ii = 0; ii < 2; ++ii) {                                              \
        const int inst = wave * 2 + ii;                                           \
        const int row = inst * 8 + l8;                                            \
        int prow = p0 + row;                                                      \
        prow = prow < NP ? prow : NP - 1;                                         \
        const unsigned short* srcB = Bb + (size_t)prow * KK + k0_ + sgrp * 8;     \
        __builtin_amdgcn_global_load_lds(                                         \
            (const __attribute__((address_space(1))) void*)srcB,                  \
            (__attribute__((address_space(3))) void*)&Bs[BUF][inst * 512], 16, 0, 0); \
    }                                                                             \
} while (0)

#define COMPUTE(BUF) do {                                                         \
    _Pragma("unroll")                                                             \
    for (int kk = 0; kk < 2; ++kk) {                                              \
        short8 a[4], bfr[2];                                                      \
        const int g8 = (((kk * 4) + (lane >> 4)) ^ (lane & 7)) << 3;              \
        const int rA = wr * 64 + (lane & 15);                                     \
        const int rB = wc * 32 + (lane & 15);                                     \
        _Pragma("unroll")                                                         \
        for (int m = 0; m < 4; ++m)                                               \
            a[m] = *(const short8*)&As[BUF][(rA + m * 16) * 64 + g8];             \
        _Pragma("unroll")                                                         \
        for (int n = 0; n < 2; ++n)                                               \
            bfr[n] = *(const short8*)&Bs[BUF][(rB + n * 16) * 64 + g8];           \
        _Pragma("unroll")                                                         \
        for (int m = 0; m < 4; ++m)                                               \
            _Pragma("unroll")                                                     \
            for (int n = 0; n < 2; ++n)                                           \
                acc[m][n] = __builtin_amdgcn_mfma_f32_16x16x32_bf16(              \
                    a[m], bfr[n], acc[m][n], 0, 0, 0);                            \
    }                                                                             \
} while (0)

    STAGE(0, 0);
    __syncthreads();

    int cur = 0;
#pragma unroll 1
    for (int kt = 0; kt < 35; ++kt) {
        STAGE(cur ^ 1, kt + 1);      // next-tile loads fly under this tile's MFMA
        COMPUTE(cur);
        __syncthreads();             // drains vmcnt(0)+lgkmcnt(0)
        cur ^= 1;
    }
    COMPUTE(cur);

#undef STAGE
#undef COMPUTE

    float* ob = out + ((size_t)mimg * OCH + g * OUTG) * NP;
    const int o0 = m0 + wr * 64 + ((lane >> 4) << 2);
    const int pc = p0 + wc * 32 + (lane & 15);
#pragma unroll
    for (int n = 0; n < 2; ++n) {
        int p = pc + n * 16;
        if (p >= NP) continue;
#pragma unroll
        for (int m = 0; m < 4; ++m) {
#pragma unroll
            for (int r = 0; r < 4; ++r)
                ob[(size_t)(o0 + m * 16 + r) * NP + p] = acc[m][n][r];
        }
    }
}

extern "C" void kernel_launch(void* const* d_in, const int* in_sizes, int n_in,
                              void* d_out, int out_size, void* d_ws, size_t ws_size,
                              hipStream_t stream) {
    const float* x   = (const float*)d_in[0];
    const float* tf  = (const float*)d_in[1];
    const float* off = (const float*)d_in[2];
    float* out = (float*)d_out;

    unsigned short* xt  = (unsigned short*)d_ws;                    // [16][1296][2304] bf16
    unsigned short* wbf = xt + (size_t)NB * NP * KK;                // [1024][2304] bf16

    hipLaunchKernelGGL(cvt_filter, dim3(OCH), dim3(256), 0, stream, tf, wbf);
    hipLaunchKernelGGL(sample_kernel, dim3(NB * 8 * HH), dim3(256), 0, stream, x, off, xt);
    hipLaunchKernelGGL(gemm_kernel, dim3(672), dim3(256), 0, stream, wbf, xt, out);
}